// Round 1
// baseline (682.718 us; speedup 1.0000x reference)
//
#include <hip/hip_runtime.h>
#include <hip/hip_bf16.h>

typedef __bf16 bf16;
typedef bf16 bf16x8 __attribute__((ext_vector_type(8)));
typedef float f32x4 __attribute__((ext_vector_type(4)));

#define D 128

// ---------------- prep: transpose + bf16-convert weights ----------------
__global__ void prep_kernel(const float* __restrict__ V1, const float* __restrict__ W1,
                            bf16* __restrict__ V1t, bf16* __restrict__ W1t) {
  int i = blockIdx.x * 256 + threadIdx.x;
  if (i < 384 * 384) { int k = i / 384, n = i % 384; V1t[n * 384 + k] = (bf16)V1[i]; }
  if (i < 128 * 128) { int k = i >> 7, n = i & 127;  W1t[n * 128 + k] = (bf16)W1[i]; }
}

// ---------------- compact: keep only edges whose src < bs ----------------
// (edges with src >= bs cannot affect the output: signal only feeds rows < bs)
__global__ void compact_kernel(const int* __restrict__ ei, int E, int bs,
                               int* __restrict__ count, int* __restrict__ list) {
  int e = blockIdx.x * 256 + threadIdx.x;
  if (e < E && ei[e] < bs) {
    int p = atomicAdd(count, 1);
    list[p] = e;
  }
}

// ---------------- node MLP: logits = relu(x@W1+b1)@W2 + b2 ----------------
__global__ __launch_bounds__(256, 2) void node_kernel(
    const float* __restrict__ x, const bf16* __restrict__ W1t,
    const float* __restrict__ b1, const float* __restrict__ W2,
    const float* __restrict__ b2, float* __restrict__ logits, int bs)
{
  __shared__ bf16 sA[64][136];   // 128 + 8 pad (2-way bank alias = free)
  __shared__ float sOut0[64], sOut1[64];

  int tid = threadIdx.x;
  if (tid < 64) { sOut0[tid] = 0.f; sOut1[tid] = 0.f; }

  {  // stage 64 consecutive node rows, fp32 -> bf16
    int g = tid >> 5, fl = tid & 31;
#pragma unroll
    for (int i = 0; i < 8; ++i) {
      int row = i * 8 + g;
      const float4* base = (const float4*)(x + (size_t)(blockIdx.x * 64 + row) * D);
      float4 v = base[fl];
      union { bf16 h[4]; uint2 u; } cv;
      cv.h[0] = (bf16)v.x; cv.h[1] = (bf16)v.y; cv.h[2] = (bf16)v.z; cv.h[3] = (bf16)v.w;
      *(uint2*)&sA[row][fl * 4] = cv.u;
    }
  }
  __syncthreads();

  int wave = tid >> 6, lane = tid & 63;
  int l15 = lane & 15, quad = lane >> 4;

  f32x4 acc[2][4];
#pragma unroll
  for (int ct = 0; ct < 2; ++ct)
#pragma unroll
    for (int rt = 0; rt < 4; ++rt)
      acc[ct][rt] = (f32x4){0.f, 0.f, 0.f, 0.f};

  for (int kc = 0; kc < 4; ++kc) {
    int k = kc * 32 + quad * 8;
    bf16x8 a[4], b[2];
#pragma unroll
    for (int rt = 0; rt < 4; ++rt)
      a[rt] = *(const bf16x8*)&sA[rt * 16 + l15][k];
#pragma unroll
    for (int ct = 0; ct < 2; ++ct)
      b[ct] = *(const bf16x8*)&W1t[(size_t)(wave * 32 + ct * 16 + l15) * 128 + k];
#pragma unroll
    for (int ct = 0; ct < 2; ++ct)
#pragma unroll
      for (int rt = 0; rt < 4; ++rt)
        acc[ct][rt] = __builtin_amdgcn_mfma_f32_16x16x32_bf16(a[rt], b[ct], acc[ct][rt], 0, 0, 0);
  }

  float bc[2], w0[2], w1[2];
#pragma unroll
  for (int ct = 0; ct < 2; ++ct) {
    int n = wave * 32 + ct * 16 + l15;
    bc[ct] = b1[n]; w0[ct] = W2[n * 2]; w1[ct] = W2[n * 2 + 1];
  }
#pragma unroll
  for (int rt = 0; rt < 4; ++rt) {
#pragma unroll
    for (int reg = 0; reg < 4; ++reg) {
      float p0 = 0.f, p1 = 0.f;
#pragma unroll
      for (int ct = 0; ct < 2; ++ct) {
        float h = fmaxf(acc[ct][rt][reg] + bc[ct], 0.f);
        p0 += h * w0[ct]; p1 += h * w1[ct];
      }
      p0 += __shfl_xor(p0, 1, 16); p0 += __shfl_xor(p0, 2, 16);
      p0 += __shfl_xor(p0, 4, 16); p0 += __shfl_xor(p0, 8, 16);
      p1 += __shfl_xor(p1, 1, 16); p1 += __shfl_xor(p1, 2, 16);
      p1 += __shfl_xor(p1, 4, 16); p1 += __shfl_xor(p1, 8, 16);
      if (l15 == 0) {
        int row = rt * 16 + quad * 4 + reg;
        atomicAdd(&sOut0[row], p0);
        atomicAdd(&sOut1[row], p1);
      }
    }
  }
  __syncthreads();
  if (tid < 64) {
    int node = blockIdx.x * 64 + tid;
    if (node < bs) {
      logits[2 * node]     = sOut0[tid] + b2[0];
      logits[2 * node + 1] = sOut1[tid] + b2[1];
    }
  }
}

// ---------------- edge MLP + sigmoid + segment_max ----------------
__global__ __launch_bounds__(256, 2) void edge_kernel(
    const float* __restrict__ x, const float* __restrict__ ea,
    const bf16* __restrict__ V1t, const float* __restrict__ bv1,
    const float* __restrict__ V2, const float* __restrict__ bv2,
    const int* __restrict__ ei, const int* __restrict__ count,
    const int* __restrict__ list, float* __restrict__ signal,
    int E, int bs)
{
  __shared__ bf16 sA[64][392];   // 384 + 8 pad; 49 KiB
  __shared__ float sScore[64];
  __shared__ int sSrc[64], sDst[64], sE[64];

  int nvalid = *count - (int)(blockIdx.x * 64);
  if (nvalid <= 0) return;       // uniform exit, before any barrier
  if (nvalid > 64) nvalid = 64;

  int tid = threadIdx.x;
  if (tid < 64) {
    int e = 0;
    if (tid < nvalid) e = list[blockIdx.x * 64 + tid];
    sE[tid] = e;
    sSrc[tid] = ei[e];
    sDst[tid] = ei[E + e];
    sScore[tid] = 0.f;
  }
  __syncthreads();

  {  // gather [x[src] | x[dst] | edge_attr] -> LDS bf16
    int g = tid >> 5, fl = tid & 31;
#pragma unroll
    for (int i = 0; i < 24; ++i) {
      int t = i * 8 + g;        // 0..191 = 64 rows x 3 segments
      int row = t & 63, seg = t >> 6;
      const float* base;
      if (seg == 0)      base = x  + (size_t)sSrc[row] * D;
      else if (seg == 1) base = x  + (size_t)sDst[row] * D;
      else               base = ea + (size_t)sE[row]   * D;
      float4 v = ((const float4*)base)[fl];
      union { bf16 h[4]; uint2 u; } cv;
      cv.h[0] = (bf16)v.x; cv.h[1] = (bf16)v.y; cv.h[2] = (bf16)v.z; cv.h[3] = (bf16)v.w;
      *(uint2*)&sA[row][seg * 128 + fl * 4] = cv.u;
    }
  }
  __syncthreads();

  int wave = tid >> 6, lane = tid & 63;
  int l15 = lane & 15, quad = lane >> 4;

  f32x4 acc[6][4];               // [col-tile][row-tile]
#pragma unroll
  for (int ct = 0; ct < 6; ++ct)
#pragma unroll
    for (int rt = 0; rt < 4; ++rt)
      acc[ct][rt] = (f32x4){0.f, 0.f, 0.f, 0.f};

  const bf16* Bbase = V1t + (size_t)(wave * 96 + l15) * 384 + quad * 8;

  for (int kc = 0; kc < 12; ++kc) {
    int k = kc * 32 + quad * 8;
    bf16x8 a[4], b[6];
#pragma unroll
    for (int rt = 0; rt < 4; ++rt)
      a[rt] = *(const bf16x8*)&sA[rt * 16 + l15][k];
#pragma unroll
    for (int ct = 0; ct < 6; ++ct)
      b[ct] = *(const bf16x8*)(Bbase + (size_t)ct * 16 * 384 + kc * 32);
#pragma unroll
    for (int ct = 0; ct < 6; ++ct)
#pragma unroll
      for (int rt = 0; rt < 4; ++rt)
        acc[ct][rt] = __builtin_amdgcn_mfma_f32_16x16x32_bf16(a[rt], b[ct], acc[ct][rt], 0, 0, 0);
  }

  // epilogue: +bv1, relu, dot V2, cross-lane reduce, sigmoid, atomicMax
  float bvc[6], v2c[6];
#pragma unroll
  for (int ct = 0; ct < 6; ++ct) {
    int n = wave * 96 + ct * 16 + l15;
    bvc[ct] = bv1[n]; v2c[ct] = V2[n];
  }
#pragma unroll
  for (int rt = 0; rt < 4; ++rt) {
#pragma unroll
    for (int reg = 0; reg < 4; ++reg) {
      float p = 0.f;
#pragma unroll
      for (int ct = 0; ct < 6; ++ct)
        p += fmaxf(acc[ct][rt][reg] + bvc[ct], 0.f) * v2c[ct];
      p += __shfl_xor(p, 1, 16);
      p += __shfl_xor(p, 2, 16);
      p += __shfl_xor(p, 4, 16);
      p += __shfl_xor(p, 8, 16);
      if (l15 == 0)
        atomicAdd(&sScore[rt * 16 + quad * 4 + reg], p);
    }
  }
  __syncthreads();
  if (tid < nvalid) {
    float sc = sScore[tid] + bv2[0];
    float sig = 1.f / (1.f + __expf(-sc));
    // sigmoid > 0, signal init 0: positive-float int compare == float max
    atomicMax((int*)&signal[sSrc[tid]], __float_as_int(sig));
  }
}

// ---------------- combine + labels ----------------
__global__ void combine_kernel(const float* __restrict__ logits, const float* __restrict__ signal,
                               const int* __restrict__ y, const float* __restrict__ ecw,
                               float* __restrict__ out, int bs) {
  int i = blockIdx.x * 256 + threadIdx.x;
  if (i < bs) {
    out[2 * i]     = logits[2 * i];
    out[2 * i + 1] = logits[2 * i + 1] + ecw[0] * signal[i];
    out[2 * bs + i] = (float)y[i];
  }
}

extern "C" void kernel_launch(void* const* d_in, const int* in_sizes, int n_in,
                              void* d_out, int out_size, void* d_ws, size_t ws_size,
                              hipStream_t stream) {
  const float* x   = (const float*)d_in[0];
  const float* ea  = (const float*)d_in[1];
  const float* W1  = (const float*)d_in[2];
  const float* b1  = (const float*)d_in[3];
  const float* W2  = (const float*)d_in[4];
  const float* b2  = (const float*)d_in[5];
  const float* V1  = (const float*)d_in[6];
  const float* bv1 = (const float*)d_in[7];
  const float* V2  = (const float*)d_in[8];
  const float* bv2 = (const float*)d_in[9];
  const float* ecw = (const float*)d_in[10];
  const int*   ei  = (const int*)d_in[11];
  const int*   y   = (const int*)d_in[12];

  int E  = in_sizes[1] / D;
  int bs = out_size / 3;         // 2*bs logits + bs labels

  char* ws = (char*)d_ws;
  size_t off = 0;
  bf16* V1t = (bf16*)(ws + off); off += (size_t)384 * 384 * 2;   // 294912
  bf16* W1t = (bf16*)(ws + off); off += (size_t)128 * 128 * 2;   // 32768
  float* signal = (float*)(ws + off); off += (size_t)bs * 4;
  float* logits = (float*)(ws + off); off += (size_t)bs * 8;
  int* count = (int*)(ws + off); off += 16;
  int* list  = (int*)(ws + off); off += (size_t)E * 4;

  hipMemsetAsync(signal, 0, (size_t)bs * 4, stream);
  hipMemsetAsync(count, 0, 4, stream);

  prep_kernel<<<(384 * 384 + 255) / 256, 256, 0, stream>>>(V1, W1, V1t, W1t);
  compact_kernel<<<(E + 255) / 256, 256, 0, stream>>>(ei, E, bs, count, list);
  node_kernel<<<(bs + 63) / 64, 256, 0, stream>>>(x, W1t, b1, W2, b2, logits, bs);
  edge_kernel<<<(E + 63) / 64, 256, 0, stream>>>(x, ea, V1t, bv1, V2, bv2,
                                                 ei, count, list, signal, E, bs);
  combine_kernel<<<(bs + 255) / 256, 256, 0, stream>>>(logits, signal, y, ecw,
                                                       (float*)d_out, bs);
}